// Round 7
// baseline (399.007 us; speedup 1.0000x reference)
//
#include <hip/hip_runtime.h>

typedef unsigned long long u64;
typedef unsigned int u32;

#define FEAT_W 100
#define NANCH 9
#define NTOT 57600
#define NPAD 65536
#define PRE_NMS 6000
#define POST_NMS 300
#define NWORDS 94
#define CH_STRIDE 6400
#define CHUNK 1024
#define CAP 6144
#define WARM_ROWS 3072

__constant__ double c_base[9][4] = {
    {-84.0, -40.0, 99.0, 55.0},    {-176.0, -88.0, 191.0, 103.0},
    {-360.0, -184.0, 375.0, 199.0},{-56.0, -56.0, 71.0, 71.0},
    {-120.0, -120.0, 135.0, 135.0},{-248.0, -248.0, 263.0, 263.0},
    {-36.0, -80.0, 51.0, 95.0},    {-80.0, -168.0, 95.0, 183.0},
    {-168.0, -344.0, 183.0, 359.0}};

struct BoxD { double x1, y1, x2, y2; };

__device__ __forceinline__ BoxD decode_box(int i, const float* __restrict__ bbox,
                                           double imw1, double imh1) {
  int pos = i / NANCH;
  int a = i - pos * NANCH;
  int h = pos / FEAT_W;
  int w = pos - h * FEAT_W;
  double ax1 = c_base[a][0] + 16.0 * (double)w;
  double ay1 = c_base[a][1] + 16.0 * (double)h;
  double ax2 = c_base[a][2] + 16.0 * (double)w;
  double ay2 = c_base[a][3] + 16.0 * (double)h;
  double wd = ax2 - ax1 + 1.0;
  double hg = ay2 - ay1 + 1.0;
  double cx = ax1 + 0.5 * wd;
  double cy = ay1 + 0.5 * hg;
  const float* bp = bbox + (size_t)(4 * a) * CH_STRIDE + pos;
  double dx = (double)bp[0];
  double dy = (double)bp[CH_STRIDE];
  double dw = (double)bp[2 * CH_STRIDE];
  double dh = (double)bp[3 * CH_STRIDE];
  double pcx = dx * wd + cx;
  double pcy = dy * hg + cy;
  double pw = exp(dw) * wd;
  double ph = exp(dh) * hg;
  BoxD b;
  b.x1 = fmin(fmax(pcx - 0.5 * pw, 0.0), imw1);
  b.y1 = fmin(fmax(pcy - 0.5 * ph, 0.0), imh1);
  b.x2 = fmin(fmax(pcx + 0.5 * pw, 0.0), imw1);
  b.y2 = fmin(fmax(pcy + 0.5 * ph, 0.0), imh1);
  return b;
}

__device__ __forceinline__ u64 score_key(int i, const float* __restrict__ cls,
                                         const float* __restrict__ bbox,
                                         double imw1, double imh1) {
  BoxD b = decode_box(i, bbox, imw1, imh1);
  bool valid = (b.x2 - b.x1 + 1.0 >= 16.0) && (b.y2 - b.y1 + 1.0 >= 16.0);
  int pos = i / NANCH;
  int a = i - pos * NANCH;
  double c0 = (double)cls[(size_t)(2 * a) * CH_STRIDE + pos];
  double c1 = (double)cls[(size_t)(2 * a + 1) * CH_STRIDE + pos];
  double m = fmax(c0, c1);
  double e0 = exp(c0 - m), e1 = exp(c1 - m);
  double s = e1 / (e0 + e1);
  double masked = valid ? s : (double)(-1e30f);
  u64 u = (u64)__double_as_longlong(masked);
  return (u >> 63) ? ~u : (u | 0x8000000000000000ULL);
}

__device__ __forceinline__ bool before(u64 ka, u32 va, u64 kb, u32 vb) {
  return (ka > kb) || (ka == kb && va < vb);
}
__device__ __forceinline__ bool comes_after(u64 ka, u32 va, u64 kb, u32 vb) {
  return (ka < kb) || (ka == kb && va > vb);
}

__device__ __forceinline__ int count_before(const u64* Sk, const u32* Sv, int n,
                                            u64 k, u32 v) {
  int lo = 0, hi = n;
  while (lo < hi) {
    int m = (lo + hi) >> 1;
    if (before(Sk[m], Sv[m], k, v)) lo = m + 1; else hi = m;
  }
  return lo;
}

// 64 blocks: compute 1024 keys, bitonic-sort in LDS (55 stages), write chunk.
__global__ __launch_bounds__(512) void k_score_sort(
    const float* __restrict__ cls, const float* __restrict__ bbox,
    const int* __restrict__ imh, const int* __restrict__ imw,
    u64* __restrict__ keys, u32* __restrict__ vals) {
  __shared__ u64 sk[CHUNK];
  __shared__ u32 sv[CHUNK];
  int base = blockIdx.x * CHUNK;
  double imh1 = (double)(imh[0] - 1);
  double imw1 = (double)(imw[0] - 1);
  for (int t = threadIdx.x; t < CHUNK; t += 512) {
    int i = base + t;
    if (i < NTOT) { sk[t] = score_key(i, cls, bbox, imw1, imh1); sv[t] = (u32)i; }
    else { sk[t] = 0ULL; sv[t] = (u32)i; }
  }
  __syncthreads();
  for (int k = 2; k <= CHUNK; k <<= 1) {
    for (int j = k >> 1; j > 0; j >>= 1) {
      int t = threadIdx.x;
      int i = ((t & ~(j - 1)) << 1) | (t & (j - 1));
      int l = i | j;
      bool up = ((i & k) == 0);
      u64 ka = sk[i], kb = sk[l];
      u32 va = sv[i], vb = sv[l];
      if (comes_after(ka, va, kb, vb) == up) { sk[i] = kb; sv[i] = vb; sk[l] = ka; sv[l] = va; }
      __syncthreads();
    }
  }
  for (int t = threadIdx.x; t < CHUNK; t += 512) { keys[base + t] = sk[t]; vals[base + t] = sv[t]; }
}

// r1: 64 lists x1024 -> 8 groups x6144 (A -> B), 8-way rank-merge (truncated).
__global__ void k_rank1(const u64* __restrict__ Ak, const u32* __restrict__ Av,
                        u64* __restrict__ Bk, u32* __restrict__ Bv) {
  int gtid = blockIdx.x * blockDim.x + threadIdx.x;
  if (gtid >= NPAD) return;
  int lst = gtid >> 10, pos = gtid & 1023, grp = lst >> 3;
  u64 k = Ak[gtid]; u32 v = Av[gtid];
  int rank = pos;
  int b0 = grp << 3;
  #pragma unroll
  for (int s = 0; s < 8; ++s)
    if ((b0 + s) != lst)
      rank += count_before(Ak + (size_t)(b0 + s) * 1024, Av + (size_t)(b0 + s) * 1024, 1024, k, v);
  if (rank < CAP) { Bk[(size_t)grp * CAP + rank] = k; Bv[(size_t)grp * CAP + rank] = v; }
}

// r2: 8 lists x6144 -> top-6000, 8-way rank-merge fused with box decode.
__global__ void k_rank2(const u64* __restrict__ Bk, const u32* __restrict__ Bv,
                        const float* __restrict__ bbox, const int* __restrict__ imh,
                        const int* __restrict__ imw, double4* __restrict__ sboxes) {
  int gtid = blockIdx.x * blockDim.x + threadIdx.x;
  if (gtid >= 8 * CAP) return;
  int lst = gtid / CAP, pos = gtid - lst * CAP;
  u64 k = Bk[gtid]; u32 v = Bv[gtid];
  int rank = pos;
  #pragma unroll
  for (int s = 0; s < 8; ++s)
    if (s != lst)
      rank += count_before(Bk + (size_t)s * CAP, Bv + (size_t)s * CAP, CAP, k, v);
  if (rank < PRE_NMS) {
    double imh1 = (double)(imh[0] - 1);
    double imw1 = (double)(imw[0] - 1);
    BoxD b = decode_box((int)v, bbox, imw1, imh1);
    sboxes[rank] = make_double4(b.x1, b.y1, b.x2, b.y2);
  }
}

// IoU bitmask; diagonal tiles additionally written compactly to diagbuf.
__global__ void k_mask(const double4* __restrict__ sboxes, u64* __restrict__ mask,
                       u64* __restrict__ diagbuf) {
  __shared__ double4 cb[64];
  int bc = blockIdx.x, br = blockIdx.y;
  int t = threadIdx.x;
  int j0 = bc * 64;
  int jt = j0 + t;
  cb[t] = (jt < PRE_NMS) ? sboxes[jt] : make_double4(0.0, 0.0, 0.0, 0.0);
  __syncthreads();
  int i = br * 64 + t;
  if (i >= PRE_NMS) return;
  double4 rb = sboxes[i];
  double areai = (rb.z - rb.x) * (rb.w - rb.y);
  u64 bits = 0;
  int cmax = min(64, PRE_NMS - j0);
  for (int c = 0; c < cmax; ++c) {
    int j = j0 + c;
    if (j <= i) continue;
    double4 cbx = cb[c];
    double xx1 = fmax(rb.x, cbx.x), yy1 = fmax(rb.y, cbx.y);
    double xx2 = fmin(rb.z, cbx.z), yy2 = fmin(rb.w, cbx.w);
    double w = fmax(xx2 - xx1, 0.0), h = fmax(yy2 - yy1, 0.0);
    double inter = w * h;
    double areaj = (cbx.z - cbx.x) * (cbx.w - cbx.y);
    double iou = inter / (areai + areaj - inter);
    if (iou > 0.7) bits |= (1ULL << c);
  }
  mask[(size_t)i * NWORDS + bc] = bits;
  if (br == bc) diagbuf[(size_t)bc * 64 + t] = bits;
}

// Chunk-tile greedy NMS. Wave 0 scans (diag words from compact L2-hot diagbuf,
// kept-row gather from mask). Waves 1..7 bulk-stream mask rows 0..WARM_ROWS
// into the local XCD L2 (XOR sink defeats DCE; no sync needed, pure warming).
__global__ __launch_bounds__(512) void k_scan(const u64* __restrict__ mask,
                                              const u64* __restrict__ diagbuf,
                                              const double4* __restrict__ sboxes,
                                              float* __restrict__ out,
                                              u64* __restrict__ sink_out) {
  __shared__ int keepL[POST_NMS];
  int tid = threadIdx.x;
  int lane = tid & 63;
  int wave = tid >> 6;
  for (int r = tid; r < POST_NMS; r += 512) keepL[r] = 0;
  __syncthreads();

  if (wave == 0) {
    int kreg0 = 0, kreg1 = 0, kreg2 = 0, kreg3 = 0, kreg4 = 0;
    int nkeep = 0;
    u64 dw_cur = diagbuf[lane]; // chunk 0 diag word
    bool done = false;
    for (int w = 0; w < NWORDS && !done; ++w) {
      // gather OR of kept rows' word w (<=5 independent loads, one wait)
      int nq = (nkeep + 63) >> 6;
      u64 g0 = 0, g1 = 0, g2 = 0, g3 = 0, g4 = 0;
      if (nq > 0) g0 = mask[(size_t)kreg0 * NWORDS + w];
      if (nq > 1) g1 = mask[(size_t)kreg1 * NWORDS + w];
      if (nq > 2) g2 = mask[(size_t)kreg2 * NWORDS + w];
      if (nq > 3) g3 = mask[(size_t)kreg3 * NWORDS + w];
      if (nq > 4) g4 = mask[(size_t)kreg4 * NWORDS + w];
      // prefetch next chunk's diag word (coalesced, L2-hot)
      u64 dw_next = 0;
      if (w + 1 < NWORDS) dw_next = diagbuf[(size_t)((w + 1) << 6) + lane];
      u64 orv = 0;
      if (lane < nkeep) orv |= g0;
      if (64 + lane < nkeep) orv |= g1;
      if (128 + lane < nkeep) orv |= g2;
      if (192 + lane < nkeep) orv |= g3;
      if (256 + lane < nkeep) orv |= g4;
      #pragma unroll
      for (int m = 32; m; m >>= 1) orv |= __shfl_xor(orv, m);

      u64 valid = (w == NWORDS - 1) ? ((1ULL << 48) - 1) : ~0ULL;
      u64 alive = ~orv & valid;
      while (alive) {
        int b = __builtin_ctzll(alive);
        int K = (w << 6) + b;
        if (lane == 0) keepL[nkeep] = K;
        int q = nkeep >> 6, l = nkeep & 63;
        if (lane == l) {
          if (q == 0) kreg0 = K;
          else if (q == 1) kreg1 = K;
          else if (q == 2) kreg2 = K;
          else if (q == 3) kreg3 = K;
          else kreg4 = K;
        }
        ++nkeep;
        if (nkeep >= POST_NMS) { done = true; break; }
        u64 rb = __shfl(dw_cur, b);
        alive &= ~rb;
        alive &= ~(1ULL << b);
      }
      dw_cur = dw_next;
    }
  } else {
    // streamers: warm mask rows into local L2
    int sw = wave - 1; // 0..6
    u64 acc = 0;
    for (int r = sw; r < WARM_ROWS; r += 7) {
      const u64* rp = mask + (size_t)r * NWORDS;
      acc ^= rp[lane];
      if (lane < NWORDS - 64) acc ^= rp[64 + lane];
    }
    if (lane == 0) sink_out[sw] = acc;
  }
  __syncthreads();

  for (int r = tid; r < POST_NMS; r += 512) {
    int kk = keepL[r];
    double4 b = sboxes[kk];
    float* o = out + r * 5;
    o[0] = 0.0f;
    o[1] = (float)b.x;
    o[2] = (float)b.y;
    o[3] = (float)b.z;
    o[4] = (float)b.w;
  }
}

extern "C" void kernel_launch(void* const* d_in, const int* in_sizes, int n_in,
                              void* d_out, int out_size, void* d_ws, size_t ws_size,
                              hipStream_t stream) {
  const float* cls = (const float*)d_in[0];
  const float* bbox = (const float*)d_in[1];
  const int* imh = (const int*)d_in[2];
  const int* imw = (const int*)d_in[3];
  float* out = (float*)d_out;

  // Workspace:
  // [0, 192512)           sboxes (6016 double4)
  // [192512, 4704512)     mask (6000*94 u64); A and B key/val buffers overlay
  //                       the front of mask (both dead before k_mask runs):
  //   Ak 192512..716800, Av 716800..978944
  //   Bk 978944..1372160, Bv 1372160..1568768
  // [4704512, 4704576)    streamer sinks (8 u64)
  // [4704576, 4752704)    diagbuf (94*64 u64)
  char* p = (char*)d_ws;
  double4* sboxes = (double4*)p;
  char* mb = p + 192512;
  u64* maskbuf = (u64*)mb;
  u64* Ak = (u64*)mb;
  u32* Av = (u32*)(mb + 524288);
  u64* Bk = (u64*)(mb + 786432);
  u32* Bv = (u32*)(mb + 1179648);
  u64* sink = (u64*)(p + 4704512);
  u64* diagbuf = (u64*)(p + 4704576);

  k_score_sort<<<64, 512, 0, stream>>>(cls, bbox, imh, imw, Ak, Av);
  k_rank1<<<NPAD / 256, 256, 0, stream>>>(Ak, Av, Bk, Bv);
  k_rank2<<<(8 * CAP) / 256, 256, 0, stream>>>(Bk, Bv, bbox, imh, imw, sboxes);
  k_mask<<<dim3(NWORDS, NWORDS), 64, 0, stream>>>(sboxes, maskbuf, diagbuf);
  k_scan<<<1, 512, 0, stream>>>(maskbuf, diagbuf, sboxes, out, sink);
}

// Round 8
// 311.007 us; speedup vs baseline: 1.2830x; 1.2830x over previous
//
#include <hip/hip_runtime.h>

typedef unsigned long long u64;
typedef unsigned int u32;

#define FEAT_W 100
#define NANCH 9
#define NTOT 57600
#define NPAD 65536
#define PRE_NMS 6000
#define POST_NMS 300
#define NWORDS 94
#define CH_STRIDE 6400
#define CHUNK 1024
#define CAP 6144

__constant__ double c_base[9][4] = {
    {-84.0, -40.0, 99.0, 55.0},    {-176.0, -88.0, 191.0, 103.0},
    {-360.0, -184.0, 375.0, 199.0},{-56.0, -56.0, 71.0, 71.0},
    {-120.0, -120.0, 135.0, 135.0},{-248.0, -248.0, 263.0, 263.0},
    {-36.0, -80.0, 51.0, 95.0},    {-80.0, -168.0, 95.0, 183.0},
    {-168.0, -344.0, 183.0, 359.0}};

struct BoxD { double x1, y1, x2, y2; };

__device__ __forceinline__ BoxD decode_box(int i, const float* __restrict__ bbox,
                                           double imw1, double imh1) {
  int pos = i / NANCH;
  int a = i - pos * NANCH;
  int h = pos / FEAT_W;
  int w = pos - h * FEAT_W;
  double ax1 = c_base[a][0] + 16.0 * (double)w;
  double ay1 = c_base[a][1] + 16.0 * (double)h;
  double ax2 = c_base[a][2] + 16.0 * (double)w;
  double ay2 = c_base[a][3] + 16.0 * (double)h;
  double wd = ax2 - ax1 + 1.0;
  double hg = ay2 - ay1 + 1.0;
  double cx = ax1 + 0.5 * wd;
  double cy = ay1 + 0.5 * hg;
  const float* bp = bbox + (size_t)(4 * a) * CH_STRIDE + pos;
  double dx = (double)bp[0];
  double dy = (double)bp[CH_STRIDE];
  double dw = (double)bp[2 * CH_STRIDE];
  double dh = (double)bp[3 * CH_STRIDE];
  double pcx = dx * wd + cx;
  double pcy = dy * hg + cy;
  double pw = exp(dw) * wd;
  double ph = exp(dh) * hg;
  BoxD b;
  b.x1 = fmin(fmax(pcx - 0.5 * pw, 0.0), imw1);
  b.y1 = fmin(fmax(pcy - 0.5 * ph, 0.0), imh1);
  b.x2 = fmin(fmax(pcx + 0.5 * pw, 0.0), imw1);
  b.y2 = fmin(fmax(pcy + 0.5 * ph, 0.0), imh1);
  return b;
}

__device__ __forceinline__ u64 score_key(int i, const float* __restrict__ cls,
                                         const float* __restrict__ bbox,
                                         double imw1, double imh1) {
  BoxD b = decode_box(i, bbox, imw1, imh1);
  bool valid = (b.x2 - b.x1 + 1.0 >= 16.0) && (b.y2 - b.y1 + 1.0 >= 16.0);
  int pos = i / NANCH;
  int a = i - pos * NANCH;
  double c0 = (double)cls[(size_t)(2 * a) * CH_STRIDE + pos];
  double c1 = (double)cls[(size_t)(2 * a + 1) * CH_STRIDE + pos];
  double m = fmax(c0, c1);
  double e0 = exp(c0 - m), e1 = exp(c1 - m);
  double s = e1 / (e0 + e1);
  double masked = valid ? s : (double)(-1e30f);
  u64 u = (u64)__double_as_longlong(masked);
  return (u >> 63) ? ~u : (u | 0x8000000000000000ULL);
}

__device__ __forceinline__ bool before(u64 ka, u32 va, u64 kb, u32 vb) {
  return (ka > kb) || (ka == kb && va < vb);
}
__device__ __forceinline__ bool comes_after(u64 ka, u32 va, u64 kb, u32 vb) {
  return (ka < kb) || (ka == kb && va > vb);
}

__device__ __forceinline__ int count_before(const u64* Sk, const u32* Sv, int n,
                                            u64 k, u32 v) {
  int lo = 0, hi = n;
  while (lo < hi) {
    int m = (lo + hi) >> 1;
    if (before(Sk[m], Sv[m], k, v)) lo = m + 1; else hi = m;
  }
  return lo;
}

// 64 blocks: compute 1024 keys, bitonic-sort in LDS (55 stages), write chunk.
__global__ __launch_bounds__(512) void k_score_sort(
    const float* __restrict__ cls, const float* __restrict__ bbox,
    const int* __restrict__ imh, const int* __restrict__ imw,
    u64* __restrict__ keys, u32* __restrict__ vals) {
  __shared__ u64 sk[CHUNK];
  __shared__ u32 sv[CHUNK];
  int base = blockIdx.x * CHUNK;
  double imh1 = (double)(imh[0] - 1);
  double imw1 = (double)(imw[0] - 1);
  for (int t = threadIdx.x; t < CHUNK; t += 512) {
    int i = base + t;
    if (i < NTOT) { sk[t] = score_key(i, cls, bbox, imw1, imh1); sv[t] = (u32)i; }
    else { sk[t] = 0ULL; sv[t] = (u32)i; }
  }
  __syncthreads();
  for (int k = 2; k <= CHUNK; k <<= 1) {
    for (int j = k >> 1; j > 0; j >>= 1) {
      int t = threadIdx.x;
      int i = ((t & ~(j - 1)) << 1) | (t & (j - 1));
      int l = i | j;
      bool up = ((i & k) == 0);
      u64 ka = sk[i], kb = sk[l];
      u32 va = sv[i], vb = sv[l];
      if (comes_after(ka, va, kb, vb) == up) { sk[i] = kb; sv[i] = vb; sk[l] = ka; sv[l] = va; }
      __syncthreads();
    }
  }
  for (int t = threadIdx.x; t < CHUNK; t += 512) { keys[base + t] = sk[t]; vals[base + t] = sv[t]; }
}

// r1: 64 lists x1024 -> 8 groups x6144 (A -> B), 8-way rank-merge (truncated).
__global__ void k_rank1(const u64* __restrict__ Ak, const u32* __restrict__ Av,
                        u64* __restrict__ Bk, u32* __restrict__ Bv) {
  int gtid = blockIdx.x * blockDim.x + threadIdx.x;
  if (gtid >= NPAD) return;
  int lst = gtid >> 10, pos = gtid & 1023, grp = lst >> 3;
  u64 k = Ak[gtid]; u32 v = Av[gtid];
  int rank = pos;
  int b0 = grp << 3;
  #pragma unroll
  for (int s = 0; s < 8; ++s)
    if ((b0 + s) != lst)
      rank += count_before(Ak + (size_t)(b0 + s) * 1024, Av + (size_t)(b0 + s) * 1024, 1024, k, v);
  if (rank < CAP) { Bk[(size_t)grp * CAP + rank] = k; Bv[(size_t)grp * CAP + rank] = v; }
}

// r2: 8 lists x6144 -> top-6000, 8-way rank-merge fused with box decode.
__global__ void k_rank2(const u64* __restrict__ Bk, const u32* __restrict__ Bv,
                        const float* __restrict__ bbox, const int* __restrict__ imh,
                        const int* __restrict__ imw, double4* __restrict__ sboxes) {
  int gtid = blockIdx.x * blockDim.x + threadIdx.x;
  if (gtid >= 8 * CAP) return;
  int lst = gtid / CAP, pos = gtid - lst * CAP;
  u64 k = Bk[gtid]; u32 v = Bv[gtid];
  int rank = pos;
  #pragma unroll
  for (int s = 0; s < 8; ++s)
    if (s != lst)
      rank += count_before(Bk + (size_t)s * CAP, Bv + (size_t)s * CAP, CAP, k, v);
  if (rank < PRE_NMS) {
    double imh1 = (double)(imh[0] - 1);
    double imw1 = (double)(imw[0] - 1);
    BoxD b = decode_box((int)v, bbox, imw1, imh1);
    sboxes[rank] = make_double4(b.x1, b.y1, b.x2, b.y2);
  }
}

// IoU bitmask; diagonal tiles additionally written compactly to diagbuf.
__global__ void k_mask(const double4* __restrict__ sboxes, u64* __restrict__ mask,
                       u64* __restrict__ diagbuf) {
  __shared__ double4 cb[64];
  int bc = blockIdx.x, br = blockIdx.y;
  int t = threadIdx.x;
  int j0 = bc * 64;
  int jt = j0 + t;
  cb[t] = (jt < PRE_NMS) ? sboxes[jt] : make_double4(0.0, 0.0, 0.0, 0.0);
  __syncthreads();
  int i = br * 64 + t;
  if (i >= PRE_NMS) return;
  double4 rb = sboxes[i];
  double areai = (rb.z - rb.x) * (rb.w - rb.y);
  u64 bits = 0;
  int cmax = min(64, PRE_NMS - j0);
  for (int c = 0; c < cmax; ++c) {
    int j = j0 + c;
    if (j <= i) continue;
    double4 cbx = cb[c];
    double xx1 = fmax(rb.x, cbx.x), yy1 = fmax(rb.y, cbx.y);
    double xx2 = fmin(rb.z, cbx.z), yy2 = fmin(rb.w, cbx.w);
    double w = fmax(xx2 - xx1, 0.0), h = fmax(yy2 - yy1, 0.0);
    double inter = w * h;
    double areaj = (cbx.z - cbx.x) * (cbx.w - cbx.y);
    double iou = inter / (areai + areaj - inter);
    if (iou > 0.7) bits |= (1ULL << c);
  }
  mask[(size_t)i * NWORDS + bc] = bits;
  if (br == bc) diagbuf[(size_t)bc * 64 + t] = bits;
}

// Chunk-tile greedy NMS, single wave, incremental rem + deferred row merge.
// rem bitmap in VGPRs (lane l owns words l, 64+l). Per keep: coalesced row
// load issued directly into one of 8 named pending slots (uniform switch, no
// copy -> no vmcnt wait at issue). Slots OR-merged into rem at chunk
// boundaries / when full -> one latency wait per non-empty chunk, not per
// keep. Intra-chunk suppression via diag tile word (shfl, registers only).
// NOTE: rowK[64+lane] for lane>=30 reads past the row (allocated ws); it only
// pollutes rem1 lanes 30..63, which are never consulted (words 94..127 don't
// exist; rem1 there is initialized all-ones anyway).
__global__ __launch_bounds__(64) void k_scan(const u64* __restrict__ mask,
                                             const u64* __restrict__ diagbuf,
                                             const double4* __restrict__ sboxes,
                                             float* __restrict__ out) {
  __shared__ int keepL[POST_NMS];
  int lane = threadIdx.x;
  for (int r = lane; r < POST_NMS; r += 64) keepL[r] = 0;

  u64 rem0 = 0;
  u64 rem1;
  if (lane < 29) rem1 = 0;
  else if (lane == 29) rem1 = 0xFFFF000000000000ULL; // word 93: bits 48..63 invalid
  else rem1 = ~0ULL;                                  // words >= 94 don't exist

  u64 pa0=0,pa1=0,pb0=0,pb1=0,pc0=0,pc1=0,pd0=0,pd1=0,
      pe0=0,pe1=0,pf0=0,pf1=0,pg0=0,pg1=0,ph0=0,ph1=0;
  int np = 0;
  int nkeep = 0;
  u64 dw_cur = diagbuf[lane]; // chunk 0 diag word
  bool done = false;

  for (int w = 0; w < NWORDS && !done; ++w) {
    u64 dw_next = (w + 1 < NWORDS) ? diagbuf[(size_t)((w + 1) << 6) + lane] : 0;
    // merge pending kept rows (single vmcnt wait covers all pending loads)
    rem0 |= pa0 | pb0 | pc0 | pd0 | pe0 | pf0 | pg0 | ph0;
    rem1 |= pa1 | pb1 | pc1 | pd1 | pe1 | pf1 | pg1 | ph1;
    pa0=0;pb0=0;pc0=0;pd0=0;pe0=0;pf0=0;pg0=0;ph0=0;
    pa1=0;pb1=0;pc1=0;pd1=0;pe1=0;pf1=0;pg1=0;ph1=0;
    np = 0;
    u64 word = (w < 64) ? __shfl(rem0, w) : __shfl(rem1, w - 64);
    u64 valid = (w == NWORDS - 1) ? ((1ULL << 48) - 1) : ~0ULL;
    u64 alive = ~word & valid;
    while (alive) {
      int b = __builtin_ctzll(alive);
      int K = (w << 6) + b;
      if (lane == 0) keepL[nkeep] = K;
      ++nkeep;
      if (nkeep >= POST_NMS) { done = true; break; }
      const u64* rp = mask + (size_t)K * NWORDS;
      switch (np) { // uniform branch; loads go straight into slot regs
        case 0: pa0 = rp[lane]; pa1 = rp[64 + lane]; break;
        case 1: pb0 = rp[lane]; pb1 = rp[64 + lane]; break;
        case 2: pc0 = rp[lane]; pc1 = rp[64 + lane]; break;
        case 3: pd0 = rp[lane]; pd1 = rp[64 + lane]; break;
        case 4: pe0 = rp[lane]; pe1 = rp[64 + lane]; break;
        case 5: pf0 = rp[lane]; pf1 = rp[64 + lane]; break;
        case 6: pg0 = rp[lane]; pg1 = rp[64 + lane]; break;
        default: ph0 = rp[lane]; ph1 = rp[64 + lane]; break;
      }
      if (++np == 8) { // slots full: drain
        rem0 |= pa0 | pb0 | pc0 | pd0 | pe0 | pf0 | pg0 | ph0;
        rem1 |= pa1 | pb1 | pc1 | pd1 | pe1 | pf1 | pg1 | ph1;
        pa0=0;pb0=0;pc0=0;pd0=0;pe0=0;pf0=0;pg0=0;ph0=0;
        pa1=0;pb1=0;pc1=0;pd1=0;pe1=0;pf1=0;pg1=0;ph1=0;
        np = 0;
      }
      u64 rb = __shfl(dw_cur, b);
      alive &= ~rb;
      alive &= ~(1ULL << b);
    }
    dw_cur = dw_next;
  }
  __syncthreads();

  for (int r = lane; r < POST_NMS; r += 64) {
    int kk = keepL[r];
    double4 b = sboxes[kk];
    float* o = out + r * 5;
    o[0] = 0.0f;
    o[1] = (float)b.x;
    o[2] = (float)b.y;
    o[3] = (float)b.z;
    o[4] = (float)b.w;
  }
}

extern "C" void kernel_launch(void* const* d_in, const int* in_sizes, int n_in,
                              void* d_out, int out_size, void* d_ws, size_t ws_size,
                              hipStream_t stream) {
  const float* cls = (const float*)d_in[0];
  const float* bbox = (const float*)d_in[1];
  const int* imh = (const int*)d_in[2];
  const int* imw = (const int*)d_in[3];
  float* out = (float*)d_out;

  // Workspace:
  // [0, 192512)           sboxes (6016 double4)
  // [192512, 4704512)     mask (6000*94 u64); A and B key/val buffers overlay
  //                       the front of mask (both dead before k_mask runs):
  //   Ak 192512..716800, Av 716800..978944
  //   Bk 978944..1372160, Bv 1372160..1568768
  // [4704512, 4704576)    pad (overread landing zone for last mask row)
  // [4704576, 4752704)    diagbuf (94*64 u64)
  char* p = (char*)d_ws;
  double4* sboxes = (double4*)p;
  char* mb = p + 192512;
  u64* maskbuf = (u64*)mb;
  u64* Ak = (u64*)mb;
  u32* Av = (u32*)(mb + 524288);
  u64* Bk = (u64*)(mb + 786432);
  u32* Bv = (u32*)(mb + 1179648);
  u64* diagbuf = (u64*)(p + 4704576);

  k_score_sort<<<64, 512, 0, stream>>>(cls, bbox, imh, imw, Ak, Av);
  k_rank1<<<NPAD / 256, 256, 0, stream>>>(Ak, Av, Bk, Bv);
  k_rank2<<<(8 * CAP) / 256, 256, 0, stream>>>(Bk, Bv, bbox, imh, imw, sboxes);
  k_mask<<<dim3(NWORDS, NWORDS), 64, 0, stream>>>(sboxes, maskbuf, diagbuf);
  k_scan<<<1, 64, 0, stream>>>(maskbuf, diagbuf, sboxes, out);
}

// Round 9
// 242.029 us; speedup vs baseline: 1.6486x; 1.2850x over previous
//
#include <hip/hip_runtime.h>

typedef unsigned long long u64;
typedef unsigned int u32;

#define FEAT_W 100
#define NANCH 9
#define NTOT 57600
#define NPAD 65536
#define PRE_NMS 6000
#define POST_NMS 300
#define NWORDS 94
#define CH_STRIDE 6400
#define CHUNK 1024
#define CAP 6144

__constant__ double c_base[9][4] = {
    {-84.0, -40.0, 99.0, 55.0},    {-176.0, -88.0, 191.0, 103.0},
    {-360.0, -184.0, 375.0, 199.0},{-56.0, -56.0, 71.0, 71.0},
    {-120.0, -120.0, 135.0, 135.0},{-248.0, -248.0, 263.0, 263.0},
    {-36.0, -80.0, 51.0, 95.0},    {-80.0, -168.0, 95.0, 183.0},
    {-168.0, -344.0, 183.0, 359.0}};

struct BoxD { double x1, y1, x2, y2; };

__device__ __forceinline__ BoxD decode_box(int i, const float* __restrict__ bbox,
                                           double imw1, double imh1) {
  int pos = i / NANCH;
  int a = i - pos * NANCH;
  int h = pos / FEAT_W;
  int w = pos - h * FEAT_W;
  double ax1 = c_base[a][0] + 16.0 * (double)w;
  double ay1 = c_base[a][1] + 16.0 * (double)h;
  double ax2 = c_base[a][2] + 16.0 * (double)w;
  double ay2 = c_base[a][3] + 16.0 * (double)h;
  double wd = ax2 - ax1 + 1.0;
  double hg = ay2 - ay1 + 1.0;
  double cx = ax1 + 0.5 * wd;
  double cy = ay1 + 0.5 * hg;
  const float* bp = bbox + (size_t)(4 * a) * CH_STRIDE + pos;
  double dx = (double)bp[0];
  double dy = (double)bp[CH_STRIDE];
  double dw = (double)bp[2 * CH_STRIDE];
  double dh = (double)bp[3 * CH_STRIDE];
  double pcx = dx * wd + cx;
  double pcy = dy * hg + cy;
  double pw = exp(dw) * wd;
  double ph = exp(dh) * hg;
  BoxD b;
  b.x1 = fmin(fmax(pcx - 0.5 * pw, 0.0), imw1);
  b.y1 = fmin(fmax(pcy - 0.5 * ph, 0.0), imh1);
  b.x2 = fmin(fmax(pcx + 0.5 * pw, 0.0), imw1);
  b.y2 = fmin(fmax(pcy + 0.5 * ph, 0.0), imh1);
  return b;
}

__device__ __forceinline__ u64 score_key(int i, const float* __restrict__ cls,
                                         const float* __restrict__ bbox,
                                         double imw1, double imh1) {
  BoxD b = decode_box(i, bbox, imw1, imh1);
  bool valid = (b.x2 - b.x1 + 1.0 >= 16.0) && (b.y2 - b.y1 + 1.0 >= 16.0);
  int pos = i / NANCH;
  int a = i - pos * NANCH;
  double c0 = (double)cls[(size_t)(2 * a) * CH_STRIDE + pos];
  double c1 = (double)cls[(size_t)(2 * a + 1) * CH_STRIDE + pos];
  double m = fmax(c0, c1);
  double e0 = exp(c0 - m), e1 = exp(c1 - m);
  double s = e1 / (e0 + e1);
  double masked = valid ? s : (double)(-1e30f);
  u64 u = (u64)__double_as_longlong(masked);
  return (u >> 63) ? ~u : (u | 0x8000000000000000ULL);
}

__device__ __forceinline__ bool before(u64 ka, u32 va, u64 kb, u32 vb) {
  return (ka > kb) || (ka == kb && va < vb);
}
__device__ __forceinline__ bool comes_after(u64 ka, u32 va, u64 kb, u32 vb) {
  return (ka < kb) || (ka == kb && va > vb);
}

__device__ __forceinline__ int count_before(const u64* Sk, const u32* Sv, int n,
                                            u64 k, u32 v) {
  int lo = 0, hi = n;
  while (lo < hi) {
    int m = (lo + hi) >> 1;
    if (before(Sk[m], Sv[m], k, v)) lo = m + 1; else hi = m;
  }
  return lo;
}

// 64 blocks: compute 1024 keys, bitonic-sort in LDS (55 stages), write chunk.
__global__ __launch_bounds__(512) void k_score_sort(
    const float* __restrict__ cls, const float* __restrict__ bbox,
    const int* __restrict__ imh, const int* __restrict__ imw,
    u64* __restrict__ keys, u32* __restrict__ vals) {
  __shared__ u64 sk[CHUNK];
  __shared__ u32 sv[CHUNK];
  int base = blockIdx.x * CHUNK;
  double imh1 = (double)(imh[0] - 1);
  double imw1 = (double)(imw[0] - 1);
  for (int t = threadIdx.x; t < CHUNK; t += 512) {
    int i = base + t;
    if (i < NTOT) { sk[t] = score_key(i, cls, bbox, imw1, imh1); sv[t] = (u32)i; }
    else { sk[t] = 0ULL; sv[t] = (u32)i; }
  }
  __syncthreads();
  for (int k = 2; k <= CHUNK; k <<= 1) {
    for (int j = k >> 1; j > 0; j >>= 1) {
      int t = threadIdx.x;
      int i = ((t & ~(j - 1)) << 1) | (t & (j - 1));
      int l = i | j;
      bool up = ((i & k) == 0);
      u64 ka = sk[i], kb = sk[l];
      u32 va = sv[i], vb = sv[l];
      if (comes_after(ka, va, kb, vb) == up) { sk[i] = kb; sv[i] = vb; sk[l] = ka; sv[l] = va; }
      __syncthreads();
    }
  }
  for (int t = threadIdx.x; t < CHUNK; t += 512) { keys[base + t] = sk[t]; vals[base + t] = sv[t]; }
}

// r1: 64 lists x1024 -> 8 groups x6144 (A -> B), 8-way rank-merge (truncated).
__global__ void k_rank1(const u64* __restrict__ Ak, const u32* __restrict__ Av,
                        u64* __restrict__ Bk, u32* __restrict__ Bv) {
  int gtid = blockIdx.x * blockDim.x + threadIdx.x;
  if (gtid >= NPAD) return;
  int lst = gtid >> 10, pos = gtid & 1023, grp = lst >> 3;
  u64 k = Ak[gtid]; u32 v = Av[gtid];
  int rank = pos;
  int b0 = grp << 3;
  #pragma unroll
  for (int s = 0; s < 8; ++s)
    if ((b0 + s) != lst)
      rank += count_before(Ak + (size_t)(b0 + s) * 1024, Av + (size_t)(b0 + s) * 1024, 1024, k, v);
  if (rank < CAP) { Bk[(size_t)grp * CAP + rank] = k; Bv[(size_t)grp * CAP + rank] = v; }
}

// r2: 8 lists x6144 -> top-6000, 8-way rank-merge fused with box decode.
__global__ void k_rank2(const u64* __restrict__ Bk, const u32* __restrict__ Bv,
                        const float* __restrict__ bbox, const int* __restrict__ imh,
                        const int* __restrict__ imw, double4* __restrict__ sboxes) {
  int gtid = blockIdx.x * blockDim.x + threadIdx.x;
  if (gtid >= 8 * CAP) return;
  int lst = gtid / CAP, pos = gtid - lst * CAP;
  u64 k = Bk[gtid]; u32 v = Bv[gtid];
  int rank = pos;
  #pragma unroll
  for (int s = 0; s < 8; ++s)
    if (s != lst)
      rank += count_before(Bk + (size_t)s * CAP, Bv + (size_t)s * CAP, CAP, k, v);
  if (rank < PRE_NMS) {
    double imh1 = (double)(imh[0] - 1);
    double imw1 = (double)(imw[0] - 1);
    BoxD b = decode_box((int)v, bbox, imw1, imh1);
    sboxes[rank] = make_double4(b.x1, b.y1, b.x2, b.y2);
  }
}

// IoU bitmask; diagonal tiles additionally written compactly to diagbuf.
__global__ void k_mask(const double4* __restrict__ sboxes, u64* __restrict__ mask,
                       u64* __restrict__ diagbuf) {
  __shared__ double4 cb[64];
  int bc = blockIdx.x, br = blockIdx.y;
  int t = threadIdx.x;
  int j0 = bc * 64;
  int jt = j0 + t;
  cb[t] = (jt < PRE_NMS) ? sboxes[jt] : make_double4(0.0, 0.0, 0.0, 0.0);
  __syncthreads();
  int i = br * 64 + t;
  if (i >= PRE_NMS) return;
  double4 rb = sboxes[i];
  double areai = (rb.z - rb.x) * (rb.w - rb.y);
  u64 bits = 0;
  int cmax = min(64, PRE_NMS - j0);
  for (int c = 0; c < cmax; ++c) {
    int j = j0 + c;
    if (j <= i) continue;
    double4 cbx = cb[c];
    double xx1 = fmax(rb.x, cbx.x), yy1 = fmax(rb.y, cbx.y);
    double xx2 = fmin(rb.z, cbx.z), yy2 = fmin(rb.w, cbx.w);
    double w = fmax(xx2 - xx1, 0.0), h = fmax(yy2 - yy1, 0.0);
    double inter = w * h;
    double areaj = (cbx.z - cbx.x) * (cbx.w - cbx.y);
    double iou = inter / (areai + areaj - inter);
    if (iou > 0.7) bits |= (1ULL << c);
  }
  mask[(size_t)i * NWORDS + bc] = bits;
  if (br == bc) diagbuf[(size_t)bc * 64 + t] = bits;
}

// Chunk-tile greedy NMS, single wave (R6 gather structure + R8 compact diag).
// Per chunk w: gather OR of kept rows' word w (keeps in VGPRs, <=5 parallel
// loads, ONE vmcnt wait — R6-verified codegen), then diag word from compact
// diagbuf (coalesced, issued AFTER gathers so the gather wait leaves it in
// flight). Intra-chunk suppression via diag tile word (shfl, registers only).
__global__ __launch_bounds__(64) void k_scan(const u64* __restrict__ mask,
                                             const u64* __restrict__ diagbuf,
                                             const double4* __restrict__ sboxes,
                                             float* __restrict__ out) {
  __shared__ int keepL[POST_NMS];
  int lane = threadIdx.x;
  for (int r = lane; r < POST_NMS; r += 64) keepL[r] = 0;

  int kreg0 = 0, kreg1 = 0, kreg2 = 0, kreg3 = 0, kreg4 = 0; // keep idx at q*64+lane
  int nkeep = 0;
  u64 dw_cur = diagbuf[lane]; // chunk 0 diag word
  bool done = false;

  for (int w = 0; w < NWORDS && !done; ++w) {
    // gather OR of kept rows' word w (independent loads, one wait)
    int nq = (nkeep + 63) >> 6;
    u64 g0 = 0, g1 = 0, g2 = 0, g3 = 0, g4 = 0;
    if (nq > 0) g0 = mask[(size_t)kreg0 * NWORDS + w];
    if (nq > 1) g1 = mask[(size_t)kreg1 * NWORDS + w];
    if (nq > 2) g2 = mask[(size_t)kreg2 * NWORDS + w];
    if (nq > 3) g3 = mask[(size_t)kreg3 * NWORDS + w];
    if (nq > 4) g4 = mask[(size_t)kreg4 * NWORDS + w];
    // next chunk's diag word: compact, coalesced; issued after the gathers so
    // the gathers' vmcnt wait leaves this load in flight.
    u64 dw_next = 0;
    if (w + 1 < NWORDS) dw_next = diagbuf[(size_t)((w + 1) << 6) + lane];
    u64 orv = 0;
    if (lane < nkeep) orv |= g0;
    if (64 + lane < nkeep) orv |= g1;
    if (128 + lane < nkeep) orv |= g2;
    if (192 + lane < nkeep) orv |= g3;
    if (256 + lane < nkeep) orv |= g4;
    #pragma unroll
    for (int m = 32; m; m >>= 1) orv |= __shfl_xor(orv, m);

    u64 valid = (w == NWORDS - 1) ? ((1ULL << 48) - 1) : ~0ULL;
    u64 alive = ~orv & valid;
    while (alive) {
      int b = __builtin_ctzll(alive);
      int K = (w << 6) + b;
      if (lane == 0) keepL[nkeep] = K;
      int q = nkeep >> 6, l = nkeep & 63;
      if (lane == l) {
        if (q == 0) kreg0 = K;
        else if (q == 1) kreg1 = K;
        else if (q == 2) kreg2 = K;
        else if (q == 3) kreg3 = K;
        else kreg4 = K;
      }
      ++nkeep;
      if (nkeep >= POST_NMS) { done = true; break; }
      u64 rb = __shfl(dw_cur, b);
      alive &= ~rb;
      alive &= ~(1ULL << b);
    }
    dw_cur = dw_next;
  }
  __syncthreads();

  for (int r = lane; r < POST_NMS; r += 64) {
    int kk = keepL[r];
    double4 b = sboxes[kk];
    float* o = out + r * 5;
    o[0] = 0.0f;
    o[1] = (float)b.x;
    o[2] = (float)b.y;
    o[3] = (float)b.z;
    o[4] = (float)b.w;
  }
}

extern "C" void kernel_launch(void* const* d_in, const int* in_sizes, int n_in,
                              void* d_out, int out_size, void* d_ws, size_t ws_size,
                              hipStream_t stream) {
  const float* cls = (const float*)d_in[0];
  const float* bbox = (const float*)d_in[1];
  const int* imh = (const int*)d_in[2];
  const int* imw = (const int*)d_in[3];
  float* out = (float*)d_out;

  // Workspace:
  // [0, 192512)           sboxes (6016 double4)
  // [192512, 4704512)     mask (6000*94 u64); A and B key/val buffers overlay
  //                       the front of mask (both dead before k_mask runs):
  //   Ak 192512..716800, Av 716800..978944
  //   Bk 978944..1372160, Bv 1372160..1568768
  // [4704512, 4704576)    pad
  // [4704576, 4752704)    diagbuf (94*64 u64)
  char* p = (char*)d_ws;
  double4* sboxes = (double4*)p;
  char* mb = p + 192512;
  u64* maskbuf = (u64*)mb;
  u64* Ak = (u64*)mb;
  u32* Av = (u32*)(mb + 524288);
  u64* Bk = (u64*)(mb + 786432);
  u32* Bv = (u32*)(mb + 1179648);
  u64* diagbuf = (u64*)(p + 4704576);

  k_score_sort<<<64, 512, 0, stream>>>(cls, bbox, imh, imw, Ak, Av);
  k_rank1<<<NPAD / 256, 256, 0, stream>>>(Ak, Av, Bk, Bv);
  k_rank2<<<(8 * CAP) / 256, 256, 0, stream>>>(Bk, Bv, bbox, imh, imw, sboxes);
  k_mask<<<dim3(NWORDS, NWORDS), 64, 0, stream>>>(sboxes, maskbuf, diagbuf);
  k_scan<<<1, 64, 0, stream>>>(maskbuf, diagbuf, sboxes, out);
}